// Round 6
// baseline (286.299 us; speedup 1.0000x reference)
//
#include <hip/hip_runtime.h>
#include <hip/hip_bf16.h>

#define D_MODEL 1024
#define SEQ 2048
#define NH 16
#define HD 64
#define DFF 4096

typedef __attribute__((ext_vector_type(8))) __bf16 bf16x8;
typedef __attribute__((ext_vector_type(4))) float f32x4;

__device__ __forceinline__ unsigned short f2bf(float f) {
    union { float f; unsigned u; } v; v.f = f;
    unsigned r = v.u + 0x7fffu + ((v.u >> 16) & 1u);
    return (unsigned short)(r >> 16);
}
__device__ __forceinline__ unsigned pack2(float a, float b) {
    return (unsigned)f2bf(a) | ((unsigned)f2bf(b) << 16);
}
__device__ __forceinline__ float bf2f(unsigned short u) {
    union { unsigned u; float f; } v; v.u = ((unsigned)u) << 16;
    return v.f;
}
__device__ __forceinline__ bf16x8 ld_frag(const unsigned short* p) {
    union { uint4 u; bf16x8 b; } c;
    c.u = *(const uint4*)p;
    return c.b;
}

// async global->LDS DMA, 16B/lane
typedef __attribute__((address_space(3))) unsigned lds_u32;
typedef const __attribute__((address_space(1))) unsigned glob_u32;
__device__ __forceinline__ void gl_lds16(const unsigned short* g, unsigned short* l) {
    __builtin_amdgcn_global_load_lds((glob_u32*)g, (lds_u32*)l, 16, 0, 0);
}

#define MFMA16(a,b,c) __builtin_amdgcn_mfma_f32_16x16x32_bf16(a,b,c,0,0,0)

// ---------------- fused weight cast+transpose: all 4 weights in one launch ----------------
__global__ __launch_bounds__(256) void wcast_all(const float* __restrict__ wq, const float* __restrict__ wo,
                                                 const float* __restrict__ wf1, const float* __restrict__ wf2,
                                                 unsigned short* __restrict__ oq, unsigned short* __restrict__ oo,
                                                 unsigned short* __restrict__ of1, unsigned short* __restrict__ of2) {
    __shared__ unsigned short lt[64][72];
    int id = blockIdx.x;
    const float* W; unsigned short* O; int K, N, nb, kb;
    if (id < 768)       { W = wq;  O = oq;  K = 1024; N = 3072; nb = id % 48; kb = id / 48; }
    else if (id < 1024) { id -= 768;  W = wo;  O = oo;  K = 1024; N = 1024; nb = id & 15; kb = id >> 4; }
    else if (id < 2048) { id -= 1024; W = wf1; O = of1; K = 1024; N = 4096; nb = id & 63; kb = id >> 6; }
    else                { id -= 2048; W = wf2; O = of2; K = 4096; N = 1024; nb = id & 15; kb = id >> 4; }
    int t = threadIdx.x;
    int r = t >> 2, c0 = (t & 3) << 4;
    const float* src = W + (size_t)(kb*64 + r) * N + nb*64 + c0;
    float4 f0 = ((const float4*)src)[0];
    float4 f1 = ((const float4*)src)[1];
    float4 f2 = ((const float4*)src)[2];
    float4 f3 = ((const float4*)src)[3];
    unsigned* dst = (unsigned*)&lt[r][c0];
    dst[0]=pack2(f0.x,f0.y); dst[1]=pack2(f0.z,f0.w);
    dst[2]=pack2(f1.x,f1.y); dst[3]=pack2(f1.z,f1.w);
    dst[4]=pack2(f2.x,f2.y); dst[5]=pack2(f2.z,f2.w);
    dst[6]=pack2(f3.x,f3.y); dst[7]=pack2(f3.z,f3.w);
    __syncthreads();
    int n_ = t >> 2, k0 = (t & 3) << 4;
    unsigned obuf[8];
#pragma unroll
    for (int i = 0; i < 8; i++)
        obuf[i] = (unsigned)lt[k0 + 2*i][n_] | ((unsigned)lt[k0 + 2*i + 1][n_] << 16);
    unsigned short* out = O + (size_t)(nb*64 + n_) * K + kb*64 + k0;
    ((uint4*)out)[0] = *(uint4*)&obuf[0];
    ((uint4*)out)[1] = *(uint4*)&obuf[4];
}

// ---------------- row LayerNorm (LN1): x[SEQ][1024] f32 -> bf16 ----------------
__global__ __launch_bounds__(256) void ln_kernel(const float* __restrict__ x,
                                                 const float* __restrict__ g,
                                                 const float* __restrict__ b,
                                                 unsigned short* __restrict__ out) {
    int row = blockIdx.x, t = threadIdx.x;
    float4 v = ((const float4*)(x + (size_t)row * D_MODEL))[t];
    float s  = v.x + v.y + v.z + v.w;
    float sq = v.x*v.x + v.y*v.y + v.z*v.z + v.w*v.w;
#pragma unroll
    for (int m = 1; m < 64; m <<= 1) { s += __shfl_xor(s, m, 64); sq += __shfl_xor(sq, m, 64); }
    __shared__ float ls[4], lq[4];
    int wave = t >> 6, lane = t & 63;
    if (lane == 0) { ls[wave] = s; lq[wave] = sq; }
    __syncthreads();
    s  = ls[0]+ls[1]+ls[2]+ls[3];
    sq = lq[0]+lq[1]+lq[2]+lq[3];
    float mu  = s * (1.0f / D_MODEL);
    float var = sq * (1.0f / D_MODEL) - mu * mu;
    float rs  = rsqrtf(var + 1e-5f);
    int c = t * 4;
    float y0 = (v.x - mu) * rs * g[c+0] + b[c+0];
    float y1 = (v.y - mu) * rs * g[c+1] + b[c+1];
    float y2 = (v.z - mu) * rs * g[c+2] + b[c+2];
    float y3 = (v.w - mu) * rs * g[c+3] + b[c+3];
    unsigned* o = (unsigned*)(out + (size_t)row * D_MODEL + c);
    o[0] = pack2(y0, y1); o[1] = pack2(y2, y3);
}

// ---------------- fused residual-reduce + LN2: x1 = x + b_out + sum(4 parts); x2n = LN(x1) ----------------
__global__ __launch_bounds__(256) void reduce_ln(const float* __restrict__ x,
                                                 const float* __restrict__ bout,
                                                 const unsigned short* __restrict__ parts,
                                                 const float* __restrict__ g,
                                                 const float* __restrict__ b,
                                                 float* __restrict__ x1,
                                                 unsigned short* __restrict__ x2n) {
    int row = blockIdx.x, t = threadIdx.x;
    int i = row * 256 + t;
    float4 v = ((const float4*)x)[i];
    float4 bb = ((const float4*)bout)[t];
    v.x += bb.x; v.y += bb.y; v.z += bb.z; v.w += bb.w;
#pragma unroll
    for (int p = 0; p < 4; p++) {
        ushort4 u = ((const ushort4*)(parts + (size_t)p * SEQ * D_MODEL))[i];
        v.x += bf2f(u.x); v.y += bf2f(u.y); v.z += bf2f(u.z); v.w += bf2f(u.w);
    }
    ((float4*)x1)[i] = v;
    float s  = v.x + v.y + v.z + v.w;
    float sq = v.x*v.x + v.y*v.y + v.z*v.z + v.w*v.w;
#pragma unroll
    for (int m = 1; m < 64; m <<= 1) { s += __shfl_xor(s, m, 64); sq += __shfl_xor(sq, m, 64); }
    __shared__ float ls[4], lq[4];
    int wave = t >> 6, lane = t & 63;
    if (lane == 0) { ls[wave] = s; lq[wave] = sq; }
    __syncthreads();
    s  = ls[0]+ls[1]+ls[2]+ls[3];
    sq = lq[0]+lq[1]+lq[2]+lq[3];
    float mu  = s * (1.0f / D_MODEL);
    float var = sq * (1.0f / D_MODEL) - mu * mu;
    float rs  = rsqrtf(var + 1e-5f);
    int c = t * 4;
    float y0 = (v.x - mu) * rs * g[c+0] + b[c+0];
    float y1 = (v.y - mu) * rs * g[c+1] + b[c+1];
    float y2 = (v.z - mu) * rs * g[c+2] + b[c+2];
    float y3 = (v.w - mu) * rs * g[c+3] + b[c+3];
    unsigned* o = (unsigned*)(x2n + (size_t)row * D_MODEL + c);
    o[0] = pack2(y0, y1); o[1] = pack2(y2, y3);
}

// ---------------- final reduce: out = x1 + b_ff2 + sum(4 partials) ----------------
__global__ __launch_bounds__(256) void reduce_ff2(const float* __restrict__ res,
                                                  const float* __restrict__ bias,
                                                  const unsigned short* __restrict__ parts,
                                                  float* __restrict__ out) {
    int i = blockIdx.x * 256 + threadIdx.x;
    float4 r = ((const float4*)res)[i];
    float4 b = ((const float4*)bias)[i & (D_MODEL/4 - 1)];
    r.x += b.x; r.y += b.y; r.z += b.z; r.w += b.w;
#pragma unroll
    for (int p = 0; p < 4; p++) {
        ushort4 u = ((const ushort4*)(parts + (size_t)p * SEQ * D_MODEL))[i];
        r.x += bf2f(u.x); r.y += bf2f(u.y); r.z += bf2f(u.z); r.w += bf2f(u.w);
    }
    ((float4*)out)[i] = r;
}

// ================== 256x256 8-phase GEMM core (m201-style) for FF1/FF2 ==================
// 512 threads = 8 waves (2M x 4N); per-wave output 128x64 (acc[8][4] = 128 VGPR).
// BK=64 processed as two K=32 half-steps; LDS = 2 bufs x (A 256x64 + B 256x64) bf16 = 128 KiB.
// Layout per buffer: A-kh0 [0,8192) A-kh1 [8192,16384) B-kh0 [16384,24576) B-kh1 [24576,32768) u16,
// each kh region [256 rows][32 k] with chunk-XOR swizzle pos = c ^ (row&3) (4x16B chunks/row).
// DMA: linear dest (lane*16B) + pre-swizzled source. Counted vmcnt(4) at every half-step
// boundary keeps the next half-step's 4 loads in flight across the barrier (T3+T4).
#define BMh 256
#define BNh 256
#define SMEM8_U16 65536   // 131072 B = 128 KiB

__device__ __forceinline__ void acc_init8(f32x4 acc[8][4]) {
    f32x4 z = {0.f, 0.f, 0.f, 0.f};
#pragma unroll
    for (int i = 0; i < 8; i++)
#pragma unroll
        for (int j = 0; j < 4; j++) acc[i][j] = z;
}

__device__ __forceinline__ void issue_half(const unsigned short* gA0, const unsigned short* gA1,
                                           const unsigned short* gB0, const unsigned short* gB1,
                                           unsigned short* smem, int s,
                                           int dA0, int dA1, int dB0, int dB1) {
    unsigned short* db = smem + ((s >> 1) & 1) * 32768 + (s & 1) * 8192;
    gl_lds16(gA0 + s*32, db + dA0);
    gl_lds16(gA1 + s*32, db + dA1);
    gl_lds16(gB0 + s*32, db + 16384 + dB0);
    gl_lds16(gB1 + s*32, db + 16384 + dB1);
}

__device__ __forceinline__ void gemm_core8ph(const unsigned short* __restrict__ A,
                                             const unsigned short* __restrict__ Bt,
                                             int K, int K0, int KS, int bm, int bn,
                                             unsigned short* smem, f32x4 acc[8][4],
                                             int w, int lane) {
    int quad = lane >> 4, lr = lane & 15;
    int wm = w >> 2, wn = w & 3;
    int t = w*64 + lane;
    int srow = t >> 2, sch = t & 3;
    // staging: per half-step 4 x gl_lds16/thread (A rows srow, 128+srow; B same).
    int r0 = srow, r1 = 128 + srow;
    int sc = sch ^ (r0 & 3);               // r1&3 == r0&3
    const unsigned short* gA0 = A  + (size_t)(bm*BMh + r0) * K + K0 + sc*8;
    const unsigned short* gA1 = A  + (size_t)(bm*BMh + r1) * K + K0 + sc*8;
    const unsigned short* gB0 = Bt + (size_t)(bn*BNh + r0) * K + K0 + sc*8;
    const unsigned short* gB1 = Bt + (size_t)(bn*BNh + r1) * K + K0 + sc*8;
    int dA0 = r0*32 + sch*8, dA1 = r1*32 + sch*8;   // dest = lane-linear within region
    // fragment offsets within a kh region: chunk' = quad ^ (row&3)
    int foA[8], foB[4];
#pragma unroll
    for (int i = 0; i < 8; i++) { int ra = wm*128 + i*16 + lr; foA[i] = ra*32 + ((quad ^ (ra & 3)))*8; }
#pragma unroll
    for (int j = 0; j < 4; j++) { int rb = wn*64 + j*16 + lr; foB[j] = rb*32 + ((quad ^ (rb & 3)))*8; }

    int T2 = KS >> 5;   // number of K=32 half-steps
    issue_half(gA0, gA1, gB0, gB1, smem, 0, dA0, dA1, dA0, dA1);
    issue_half(gA0, gA1, gB0, gB1, smem, 1, dA0, dA1, dA0, dA1);
    for (int s = 0; s < T2; s++) {
        // wait only for this half-step's 4 loads; keep the next half-step's 4 in flight
        if (s + 1 < T2) asm volatile("s_waitcnt vmcnt(4)" ::: "memory");
        else            asm volatile("s_waitcnt vmcnt(0)" ::: "memory");
        __builtin_amdgcn_s_barrier();
        if (s + 2 < T2) issue_half(gA0, gA1, gB0, gB1, smem, s + 2, dA0, dA1, dA0, dA1);
        const unsigned short* sa = smem + ((s >> 1) & 1) * 32768 + (s & 1) * 8192;
        const unsigned short* sb = sa + 16384;
        bf16x8 bfr[4], af0[4], af1[4];
#pragma unroll
        for (int j = 0; j < 4; j++) bfr[j] = ld_frag(sb + foB[j]);
#pragma unroll
        for (int i = 0; i < 4; i++) af0[i] = ld_frag(sa + foA[i]);
        __builtin_amdgcn_s_setprio(1);
#pragma unroll
        for (int i = 0; i < 4; i++)
#pragma unroll
            for (int j = 0; j < 4; j++)
                acc[i][j] = MFMA16(af0[i], bfr[j], acc[i][j]);
        __builtin_amdgcn_s_setprio(0);
#pragma unroll
        for (int i = 0; i < 4; i++) af1[i] = ld_frag(sa + foA[4 + i]);
        __builtin_amdgcn_s_setprio(1);
#pragma unroll
        for (int i = 0; i < 4; i++)
#pragma unroll
            for (int j = 0; j < 4; j++)
                acc[4 + i][j] = MFMA16(af1[i], bfr[j], acc[4 + i][j]);
        __builtin_amdgcn_s_setprio(0);
    }
}

// ---------------- FF1: 256x256 8-phase + bias + GELU -> bf16 ----------------
__global__ __launch_bounds__(512, 2) void k_gemm_ff1(const unsigned short* __restrict__ A,
                                                     const unsigned short* __restrict__ Bt,
                                                     const float* __restrict__ bias,
                                                     unsigned short* __restrict__ C,
                                                     int M, int N, int K) {
    __shared__ unsigned short smem[SMEM8_U16];
    int t = threadIdx.x, w = t >> 6, lane = t & 63;
    int bn = blockIdx.x, bm = blockIdx.y;
    int quad = lane >> 4, lr = lane & 15;
    f32x4 acc[8][4];
    acc_init8(acc);
    gemm_core8ph(A, Bt, K, 0, K, bm, bn, smem, acc, w, lane);
    int wm = w >> 2, wn = w & 3;
#pragma unroll
    for (int j = 0; j < 4; j++) {
        int col = bn*BNh + wn*64 + j*16 + lr;
        float bvv = bias[col];
#pragma unroll
        for (int i = 0; i < 8; i++) {
            int row0 = bm*BMh + wm*128 + i*16 + quad*4;
#pragma unroll
            for (int r = 0; r < 4; r++) {
                float v = acc[i][j][r] + bvv;
                v = 0.5f * v * (1.0f + erff(v * 0.70710678118654752f));
                C[(size_t)(row0 + r) * N + col] = f2bf(v);
            }
        }
    }
}

// ---------------- FF2: 256x256 8-phase, split-K=4 bf16 partials ----------------
__global__ __launch_bounds__(512, 2) void k_gemm_ff2(const unsigned short* __restrict__ A,
                                                     const unsigned short* __restrict__ Bt,
                                                     unsigned short* __restrict__ C,
                                                     int M, int N, int K) {
    __shared__ unsigned short smem[SMEM8_U16];
    int t = threadIdx.x, w = t >> 6, lane = t & 63;
    int bn = blockIdx.x, bm = blockIdx.y, kz = blockIdx.z;
    int quad = lane >> 4, lr = lane & 15;
    int KS = K >> 2;
    f32x4 acc[8][4];
    acc_init8(acc);
    gemm_core8ph(A, Bt, K, kz*KS, KS, bm, bn, smem, acc, w, lane);
    int wm = w >> 2, wn = w & 3;
    unsigned short* P = C + (size_t)kz * M * N;
#pragma unroll
    for (int j = 0; j < 4; j++) {
        int col = bn*BNh + wn*64 + j*16 + lr;
#pragma unroll
        for (int i = 0; i < 8; i++) {
            int row0 = bm*BMh + wm*128 + i*16 + quad*4;
#pragma unroll
            for (int r = 0; r < 4; r++)
                P[(size_t)(row0 + r) * N + col] = f2bf(acc[i][j][r]);
        }
    }
}

// ---------------- GEMM core v4b: TM=128 TN=128 BK=64, 512 threads, 8 waves (QKV/OP) ----------------
#define TMg 128
#define TNg 128
#define HALFg ((TMg + TNg) * 64)        // 16384 u16 = 32 KB per buffer
#define SMEM_U16 (2 * HALFg)            // 65536 B total
__device__ __forceinline__ void gemm_core512(const unsigned short* __restrict__ A,
                                             const unsigned short* __restrict__ Bt,
                                             int K, int K0, int KS, int bm, int bn,
                                             unsigned short* smem, f32x4 acc[4][4],
                                             int w, int lane) {
    int quad = lane >> 4, lr = lane & 15;
    int kg = w >> 2;
    const unsigned short* pa[2]; const unsigned short* pb[2];
    int aoff[2], boff[2];
#pragma unroll
    for (int i = 0; i < 2; i++) {
        int rl = i*64 + w*8 + (lane >> 3);
        int sc = (lane & 7) ^ (rl & 7);
        pa[i] = A  + (size_t)(bm*TMg + rl) * K + K0 + sc*8;
        pb[i] = Bt + (size_t)(bn*TNg + rl) * K + K0 + sc*8;
        aoff[i] = (i*64 + w*8) * 64;
        boff[i] = TMg*64 + (i*64 + w*8) * 64;
    }
    int wr = ((w >> 1) & 1) * 64, wc = (w & 1) * 64;
    int foA[4], foB[4];
#pragma unroll
    for (int i = 0; i < 4; i++) {
        int ra = wr + i*16 + lr;
        foA[i] = ra*64 + (((quad + 4*kg) ^ (ra & 7)))*8;
        int rb = wc + i*16 + lr;
        foB[i] = TMg*64 + rb*64 + (((quad + 4*kg) ^ (rb & 7)))*8;
    }
#pragma unroll
    for (int i = 0; i < 2; i++) { gl_lds16(pa[i], smem + aoff[i]); gl_lds16(pb[i], smem + boff[i]); }
    int bo = 0;
    int T = KS >> 6;
    for (int t = 0; t < T; t++) {
        __syncthreads();
        if (t + 1 < T) {
            int nb = bo ^ HALFg;
#pragma unroll
            for (int i = 0; i < 2; i++) {
                gl_lds16(pa[i] + (t+1)*64, smem + nb + aoff[i]);
                gl_lds16(pb[i] + (t+1)*64, smem + nb + boff[i]);
            }
        }
        const unsigned short* s = smem + bo;
        bf16x8 af[4], bfr[4];
#pragma unroll
        for (int i = 0; i < 4; i++) af[i] = ld_frag(s + foA[i]);
#pragma unroll
        for (int j = 0; j < 4; j++) bfr[j] = ld_frag(s + foB[j]);
        __builtin_amdgcn_s_setprio(1);
#pragma unroll
        for (int i = 0; i < 4; i++)
#pragma unroll
            for (int j = 0; j < 4; j++)
                acc[i][j] = MFMA16(af[i], bfr[j], acc[i][j]);
        __builtin_amdgcn_s_setprio(0);
        bo ^= HALFg;
    }
}

__device__ __forceinline__ void acc_init(f32x4 acc[4][4]) {
    f32x4 z = {0.f, 0.f, 0.f, 0.f};
#pragma unroll
    for (int i = 0; i < 4; i++)
#pragma unroll
        for (int j = 0; j < 4; j++) acc[i][j] = z;
}

// split-merge, literal-index version (rule #20 safe).
__device__ __forceinline__ void acc_merge_split(unsigned short* smem, f32x4 acc[4][4],
                                                int w, int lane) {
    float* X = (float*)smem;
    int kg = w >> 2, p = w & 3, quad = lane >> 4, lr = lane & 15;
    if (kg) {
#pragma unroll
        for (int i = 0; i < 4; i++) {
            f32x4 t0 = acc[i][0]; acc[i][0] = acc[i][2]; acc[i][2] = t0;
            f32x4 t1 = acc[i][1]; acc[i][1] = acc[i][3]; acc[i][3] = t1;
        }
    }
    __syncthreads();
    int g = (kg ^ 1) * 2;
#pragma unroll
    for (int i = 0; i < 4; i++)
#pragma unroll
        for (int r = 0; r < 4; r++) {
            int ro = (i*16 + r*4 + quad)*16 + lr;
            X[(p*4 + g    )*1024 + ro] = acc[i][2][r];
            X[(p*4 + g + 1)*1024 + ro] = acc[i][3][r];
        }
    __syncthreads();
    int k = kg * 2;
#pragma unroll
    for (int i = 0; i < 4; i++)
#pragma unroll
        for (int r = 0; r < 4; r++) {
            int ro = (i*16 + r*4 + quad)*16 + lr;
            acc[i][0][r] += X[(p*4 + k    )*1024 + ro];
            acc[i][1][r] += X[(p*4 + k + 1)*1024 + ro];
        }
}

// ---------------- QKV GEMM + fused q/k-normalize + v-transpose epilogue ----------------
__global__ __launch_bounds__(512, 4) void k_gemm_qkv(const unsigned short* __restrict__ A,
                                                     const unsigned short* __restrict__ Bt,
                                                     const float* __restrict__ bias,
                                                     unsigned short* __restrict__ qn,
                                                     unsigned short* __restrict__ kn,
                                                     unsigned short* __restrict__ vt) {
    __shared__ unsigned short smem[SMEM_U16];
    int t = threadIdx.x;
    int bn = blockIdx.x, bm = blockIdx.y;
    int w = t >> 6, lane = t & 63;
    int quad = lane >> 4, lr = lane & 15;
    f32x4 acc[4][4];
    acc_init(acc);
    gemm_core512(A, Bt, 1024, 0, 1024, bm, bn, smem, acc, w, lane);

    float* X = (float*)smem;
    int kg = w >> 2, p = w & 3;
    __syncthreads();
    if (kg == 1) {
#pragma unroll
        for (int j = 0; j < 4; j++) {
            float* slot = X + (p*4 + j)*1024;
#pragma unroll
            for (int i = 0; i < 4; i++)
#pragma unroll
                for (int r = 0; r < 4; r++)
                    slot[(i*16 + r*4 + quad)*16 + lr] = acc[i][j][r];
        }
    }
    __syncthreads();
    int wr = ((w >> 1) & 1) * 64, wc = (w & 1) * 64;
    int sec = bn >> 3, hp = bn & 7;
    if (kg == 0) {
#pragma unroll
        for (int j = 0; j < 4; j++) {
            const float* slot = X + (p*4 + j)*1024;
            float bv = bias[bn*TNg + wc + j*16 + lr];
#pragma unroll
            for (int i = 0; i < 4; i++)
#pragma unroll
                for (int r = 0; r < 4; r++)
                    acc[i][j][r] += slot[(i*16 + r*4 + quad)*16 + lr] + bv;
        }
    }

    if (sec < 2) {
        if (kg == 0) {
            int h = hp*2 + (w & 1);
            unsigned short* dst = (sec == 0) ? qn : kn;
            float mul = (sec == 0) ? 0.125f : 1.0f;   // fold 1/sqrt(HD) into q
#pragma unroll
            for (int i = 0; i < 4; i++)
#pragma unroll
                for (int r = 0; r < 4; r++) {
                    float ss = 0.f;
#pragma unroll
                    for (int j = 0; j < 4; j++) ss += acc[i][j][r]*acc[i][j][r];
                    ss += __shfl_xor(ss, 1, 64); ss += __shfl_xor(ss, 2, 64);
                    ss += __shfl_xor(ss, 4, 64); ss += __shfl_xor(ss, 8, 64);
                    float scale = mul / fmaxf(sqrtf(ss), 1e-12f);
                    int row = bm*TMg + wr + i*16 + quad*4 + r;
                    size_t base = ((size_t)h*SEQ + row) * HD;
#pragma unroll
                    for (int j = 0; j < 4; j++)
                        dst[base + j*16 + lr] = f2bf(acc[i][j][r] * scale);
                }
        }
    } else {
        __syncthreads();
        unsigned short (*lv)[136] = (unsigned short (*)[136])smem;
        if (kg == 0) {
#pragma unroll
            for (int i = 0; i < 4; i++)
#pragma unroll
                for (int j = 0; j < 4; j++)
#pragma unroll
                    for (int r = 0; r < 4; r++)
                        lv[wc + j*16 + lr][wr + i*16 + quad*4 + r] = f2bf(acc[i][j][r]);
        }
        __syncthreads();
        int d = t >> 2, l0 = (t & 3) * 32;
        unsigned short* ov = vt + ((size_t)(hp*128 + d)) * SEQ + bm*TMg + l0;
#pragma unroll
        for (int c = 0; c < 4; c++)
            ((uint4*)ov)[c] = *(uint4*)&lv[d][l0 + c*8];
    }
}

// ---------------- OP split-K partial-output GEMM (bf16 partial slices) ----------------
template<int SPLITK>
__device__ __forceinline__ void gemm_part512(const unsigned short* A, const unsigned short* Bt,
                                             unsigned short* C, int M, int N, int K) {
    __shared__ unsigned short smem[SMEM_U16];
    int t = threadIdx.x;
    int bn = blockIdx.x, bm = blockIdx.y, kz = blockIdx.z;
    int w = t >> 6, lane = t & 63;
    int quad = lane >> 4, lr = lane & 15;
    int KS = K / SPLITK;
    f32x4 acc[4][4];
    acc_init(acc);
    gemm_core512(A, Bt, K, kz*KS, KS, bm, bn, smem, acc, w, lane);
    acc_merge_split(smem, acc, w, lane);
    int kg = w >> 2, wr = ((w >> 1) & 1) * 64, wc = (w & 1) * 64;
    unsigned short* P = C + (size_t)kz * M * N;
    int col0 = bn*TNg + wc + (kg*2)*16 + lr;
    int col1 = col0 + 16;
#pragma unroll
    for (int i = 0; i < 4; i++) {
        int row0 = bm*TMg + wr + i*16 + quad*4;
#pragma unroll
        for (int r = 0; r < 4; r++) {
            P[(size_t)(row0 + r) * N + col0] = f2bf(acc[i][0][r]);
            P[(size_t)(row0 + r) * N + col1] = f2bf(acc[i][1][r]);
        }
    }
}
__global__ __launch_bounds__(512, 4) void k_gemm_op(const unsigned short* A, const unsigned short* Bt,
                                                    unsigned short* C, int M, int N, int K) {
    gemm_part512<4>(A, Bt, C, M, N, K);
}

// ---------------- attention: key-split KSPLIT=2, single-pass softmax ----------------
#define KSPLIT 2
#define KTILES (SEQ / 64 / KSPLIT)   // 16
__global__ __launch_bounds__(256) void attn_kernel(const unsigned short* __restrict__ qn,
                                                   const unsigned short* __restrict__ kn,
                                                   const unsigned short* __restrict__ vt,
                                                   const float* __restrict__ lcc,
                                                   float* __restrict__ num_ws,
                                                   float* __restrict__ den_ws) {
    __shared__ unsigned short lQP[64*64];      // Q then P (per-wave own stripe)
    __shared__ unsigned short lK[2][64*64];    // [key][d], swizzled chunks
    __shared__ unsigned short lV[2][64*64];    // [d][key], swizzled chunks
    int h = blockIdx.x, qb = blockIdx.y, kz = blockIdx.z;
    int t = threadIdx.x;
    int wave = t >> 6, lane = t & 63, quad = lane >> 4, lr = lane & 15;
    int r0 = lane >> 3;            // row within 8-row DMA group
    int ch = lane & 7;             // linear dest chunk

    const unsigned short* kn0 = kn + (size_t)h*SEQ*HD + (size_t)kz*(SEQ/KSPLIT)*HD;
    const unsigned short* vt0 = vt + (size_t)h*HD*SEQ + kz*(SEQ/KSPLIT);
    const float* lcc0 = lcc + kz*(SEQ/KSPLIT);

#pragma unroll
    for (int i = 0; i < 2; i++) {
        int rl = wave*16 + i*8 + r0;
        int ss = ch ^ (rl & 7);
        gl_lds16(qn + ((size_t)h*SEQ + qb*64 + rl)*HD + ss*8, lQP + (wave*16 + i*8)*64);
        gl_lds16(kn0 + (size_t)rl*HD + ss*8,                  lK[0] + (wave*16 + i*8)*64);
        gl_lds16(vt0 + (size_t)rl*SEQ + ss*8,                 lV[0] + (wave*16 + i*8)*64);
    }
    __syncthreads();

    bf16x8 aq0 = ld_frag(lQP + (wave*16 + lr)*64 + ((quad     ^ (lr & 7)))*8);
    bf16x8 aq1 = ld_frag(lQP + (wave*16 + lr)*64 + (((quad+4) ^ (lr & 7)))*8);

    f32x4 z = {0.f, 0.f, 0.f, 0.f};
    f32x4 oacc[4]; oacc[0]=z; oacc[1]=z; oacc[2]=z; oacc[3]=z;
    float den[4] = {0.f, 0.f, 0.f, 0.f};

    int cur = 0;
    for (int kb = 0; kb < KTILES; kb++) {
        if (kb + 1 < KTILES) {
            int nxt = cur ^ 1;
#pragma unroll
            for (int i = 0; i < 2; i++) {
                int rl = wave*16 + i*8 + r0;
                int ss = ch ^ (rl & 7);
                gl_lds16(kn0 + (size_t)(kb+1)*64*HD + (size_t)rl*HD + ss*8,
                         lK[nxt] + (wave*16 + i*8)*64);
                gl_lds16(vt0 + (size_t)rl*SEQ + (kb+1)*64 + ss*8,
                         lV[nxt] + (wave*16 + i*8)*64);
            }
        }
        float lmv[4];
#pragma unroll
        for (int j = 0; j < 4; j++) lmv[j] = 0.05f * lcc0[kb*64 + j*16 + lr];

        __builtin_amdgcn_s_setprio(1);
        const unsigned short* Kc = lK[cur];
#pragma unroll
        for (int j = 0; j < 4; j++) {
            bf16x8 b0 = ld_frag(Kc + (j*16 + lr)*64 + ((quad     ^ (lr & 7)))*8);
            bf16x8 b1 = ld_frag(Kc + (j*16 + lr)*64 + (((quad+4) ^ (lr & 7)))*8);
            f32x4 s = z;
            s = MFMA16(aq0, b0, s);
            s = MFMA16(aq1, b1, s);
#pragma unroll
            for (int r = 0; r < 4; r++) {
                float p = __expf(s[r] + lmv[j]);
                den[r] += p;
                int prow = wave*16 + quad*4 + r;
                lQP[prow*64 + (((2*j + (lr >> 3)) ^ (prow & 7)))*8 + (lr & 7)] = f2bf(p);
            }
        }
        bf16x8 ap0 = ld_frag(lQP + (wave*16 + lr)*64 + ((quad     ^ (lr & 7)))*8);
        bf16x8 ap1 = ld_frag(lQP + (wave*16 + lr)*64 + (((quad+4) ^ (lr & 7)))*8);
        const unsigned short* Vc = lV[cur];
#pragma unroll
        for (int j2 = 0; j2 < 4; j2++) {
            bf16x8 b0 = ld_frag(Vc + (j2*16 + lr)*64 + ((quad     ^ (lr & 7)))*8);
            bf16x8 b1 = ld_frag(Vc + (j2*16 + lr)*64 + (((quad+4) ^ (lr & 7)))*8);
            oacc[j2] = MFMA16(ap0, b0, oacc[j2]);
            oacc[j2] = MFMA16(ap1, b1, oacc[j2]);
        }
        __builtin_amdgcn_s_setprio(0);
        __syncthreads();
        cur ^= 1;
    }
#pragma unroll
    for (int r = 0; r < 4; r++)
#pragma unroll
        for (int m = 1; m < 16; m <<= 1) den[r] += __shfl_xor(den[r], m, 64);

    float* nump = num_ws + (((size_t)(h*32 + qb)) * KSPLIT + kz) * 4096;
#pragma unroll
    for (int j2 = 0; j2 < 4; j2++)
#pragma unroll
        for (int r = 0; r < 4; r++)
            nump[(wave*16 + quad*4 + r) * 64 + j2*16 + lr] = oacc[j2][r];
    if (lr == 0) {
        float* denp = den_ws + (((size_t)(h*32 + qb)) * KSPLIT + kz) * 64;
#pragma unroll
        for (int r = 0; r < 4; r++) denp[wave*16 + quad*4 + r] = den[r];
    }
}

// combine: out[qb*64+row][h*64+col] = sum_kz num / sum_kz den
__global__ __launch_bounds__(256) void attn_comb(const float* __restrict__ num_ws,
                                                 const float* __restrict__ den_ws,
                                                 unsigned short* __restrict__ attn) {
    int hq = blockIdx.x;          // h*32+qb
    int h = hq >> 5, qb = hq & 31;
    int t = threadIdx.x;
    int row = t >> 2, col0 = (t & 3) << 4;
    const float* n0 = num_ws + ((size_t)hq * KSPLIT) * 4096 + row*64 + col0;
    const float* n1 = n0 + 4096;
    float d = den_ws[(size_t)hq * KSPLIT * 64 + row] + den_ws[((size_t)hq * KSPLIT + 1) * 64 + row];
    float inv = 1.0f / d;
    unsigned ob[8];
#pragma unroll
    for (int i = 0; i < 4; i++) {
        float4 a = ((const float4*)n0)[i];
        float4 b = ((const float4*)n1)[i];
        ob[2*i]   = pack2((a.x + b.x) * inv, (a.y + b.y) * inv);
        ob[2*i+1] = pack2((a.z + b.z) * inv, (a.w + b.w) * inv);
    }
    unsigned short* op = attn + (size_t)(qb*64 + row) * D_MODEL + h*64 + col0;
    ((uint4*)op)[0] = *(uint4*)&ob[0];
    ((uint4*)op)[1] = *(uint4*)&ob[4];
}

// ---------------- host orchestration ----------------
extern "C" void kernel_launch(void* const* d_in, const int* in_sizes, int n_in,
                              void* d_out, int out_size, void* d_ws, size_t ws_size,
                              hipStream_t stream) {
    const float* x      = (const float*)d_in[0];
    const float* lcc    = (const float*)d_in[1];
    const float* w_qkv  = (const float*)d_in[2];
    const float* b_qkv  = (const float*)d_in[3];
    const float* w_out  = (const float*)d_in[4];
    const float* b_out  = (const float*)d_in[5];
    const float* ln1_g  = (const float*)d_in[6];
    const float* ln1_b  = (const float*)d_in[7];
    const float* ln2_g  = (const float*)d_in[8];
    const float* ln2_b  = (const float*)d_in[9];
    const float* w_ff1  = (const float*)d_in[10];
    const float* b_ff1  = (const float*)d_in[11];
    const float* w_ff2  = (const float*)d_in[12];
    const float* b_ff2  = (const float*)d_in[13];

    char* ws = (char*)d_ws;
    unsigned short* wtq  = (unsigned short*)(ws);                    // -> 6291456
    unsigned short* wto  = (unsigned short*)(ws + 6291456);          // -> 8388608
    unsigned short* wtf1 = (unsigned short*)(ws + 8388608);          // -> 16777216
    unsigned short* wtf2 = (unsigned short*)(ws + 16777216);         // -> 25165824
    unsigned short* xn   = (unsigned short*)(ws + 25165824);         // -> 29360128
    float*          x1   = (float*)(ws + 29360128);                  // 2048x1024 f32 -> 37748736
    float*          numw = (float*)(ws + 29360128);                  // alias: attn num partials (16.8MB)
    float*          denw = (float*)(ws + 46137344);                  // 256KB attn den partials
    unsigned short* hbuf = (unsigned short*)(ws + 37748736);         // 2048x4096 bf16 -> 54525952
    unsigned short* pOP  = (unsigned short*)(ws + 37748736);         // alias: 4 bf16 slices = 16MB
    unsigned short* qnb  = (unsigned short*)(ws + 54525952);         // -> 58720256
    unsigned short* knb  = (unsigned short*)(ws + 58720256);         // -> 62914560
    unsigned short* vtb  = (unsigned short*)(ws + 62914560);         // -> 67108864
    unsigned short* pFF2 = (unsigned short*)(ws);                    // alias (weights dead): exactly 16777216B
    unsigned short* attnb = xn;                                      // alias (xn dead after QKV gemm)
    unsigned short* x2n  = qnb;                                      // alias (qn dead after attention)
    float* outp = (float*)d_out;

    // Ordering (sequential stream): numw aliases x1 region — attn partials consumed by
    // attn_comb before reduce_ln writes x1. pOP (16MB, ends at qnb) overlaps numw tail and
    // denw — both dead once attn_comb ran; OP gemm runs after attn_comb. pFF2 overwrites
    // wtq/wto/wtf1 (dead), ends exactly at wtf2 (still live for FF2 reads).

    wcast_all<<<3072, 256, 0, stream>>>(w_qkv, w_out, w_ff1, w_ff2, wtq, wto, wtf1, wtf2);
    ln_kernel<<<SEQ, 256, 0, stream>>>(x, ln1_g, ln1_b, xn);
    k_gemm_qkv<<<dim3(24, 16), 512, 0, stream>>>(xn, wtq, b_qkv, qnb, knb, vtb);
    attn_kernel<<<dim3(16, 32, KSPLIT), 256, 0, stream>>>(qnb, knb, vtb, lcc, numw, denw);
    attn_comb<<<512, 256, 0, stream>>>(numw, denw, attnb);
    k_gemm_op<<<dim3(8, 16, 4), 512, 0, stream>>>(attnb, wto, pOP, SEQ, 1024, 1024);
    reduce_ln<<<SEQ, 256, 0, stream>>>(x, b_out, pOP, ln2_g, ln2_b, x1, x2n);
    k_gemm_ff1<<<dim3(16, 8), 512, 0, stream>>>(x2n, wtf1, b_ff1, hbuf, SEQ, 4096, 1024);
    k_gemm_ff2<<<dim3(4, 8, 4), 512, 0, stream>>>(hbuf, wtf2, pFF2, SEQ, 1024, 4096);
    reduce_ff2<<<SEQ*D_MODEL/1024, 256, 0, stream>>>(x1, b_ff2, pFF2, outp);
}

// Round 7
// 257.028 us; speedup vs baseline: 1.1139x; 1.1139x over previous
//
#include <hip/hip_runtime.h>
#include <hip/hip_bf16.h>

#define D_MODEL 1024
#define SEQ 2048
#define NH 16
#define HD 64
#define DFF 4096

typedef __attribute__((ext_vector_type(8))) __bf16 bf16x8;
typedef __attribute__((ext_vector_type(4))) float f32x4;

__device__ __forceinline__ unsigned short f2bf(float f) {
    union { float f; unsigned u; } v; v.f = f;
    unsigned r = v.u + 0x7fffu + ((v.u >> 16) & 1u);
    return (unsigned short)(r >> 16);
}
__device__ __forceinline__ unsigned pack2(float a, float b) {
    return (unsigned)f2bf(a) | ((unsigned)f2bf(b) << 16);
}
__device__ __forceinline__ float bf2f(unsigned short u) {
    union { unsigned u; float f; } v; v.u = ((unsigned)u) << 16;
    return v.f;
}
__device__ __forceinline__ bf16x8 ld_frag(const unsigned short* p) {
    union { uint4 u; bf16x8 b; } c;
    c.u = *(const uint4*)p;
    return c.b;
}

// async global->LDS DMA, 16B/lane
typedef __attribute__((address_space(3))) unsigned lds_u32;
typedef const __attribute__((address_space(1))) unsigned glob_u32;
__device__ __forceinline__ void gl_lds16(const unsigned short* g, unsigned short* l) {
    __builtin_amdgcn_global_load_lds((glob_u32*)g, (lds_u32*)l, 16, 0, 0);
}

#define MFMA16(a,b,c) __builtin_amdgcn_mfma_f32_16x16x32_bf16(a,b,c,0,0,0)

// ---------------- fused weight cast+transpose: all 4 weights in one launch ----------------
__global__ __launch_bounds__(256) void wcast_all(const float* __restrict__ wq, const float* __restrict__ wo,
                                                 const float* __restrict__ wf1, const float* __restrict__ wf2,
                                                 unsigned short* __restrict__ oq, unsigned short* __restrict__ oo,
                                                 unsigned short* __restrict__ of1, unsigned short* __restrict__ of2) {
    __shared__ unsigned short lt[64][72];
    int id = blockIdx.x;
    const float* W; unsigned short* O; int K, N, nb, kb;
    if (id < 768)       { W = wq;  O = oq;  K = 1024; N = 3072; nb = id % 48; kb = id / 48; }
    else if (id < 1024) { id -= 768;  W = wo;  O = oo;  K = 1024; N = 1024; nb = id & 15; kb = id >> 4; }
    else if (id < 2048) { id -= 1024; W = wf1; O = of1; K = 1024; N = 4096; nb = id & 63; kb = id >> 6; }
    else                { id -= 2048; W = wf2; O = of2; K = 4096; N = 1024; nb = id & 15; kb = id >> 4; }
    int t = threadIdx.x;
    int r = t >> 2, c0 = (t & 3) << 4;
    const float* src = W + (size_t)(kb*64 + r) * N + nb*64 + c0;
    float4 f0 = ((const float4*)src)[0];
    float4 f1 = ((const float4*)src)[1];
    float4 f2 = ((const float4*)src)[2];
    float4 f3 = ((const float4*)src)[3];
    unsigned* dst = (unsigned*)&lt[r][c0];
    dst[0]=pack2(f0.x,f0.y); dst[1]=pack2(f0.z,f0.w);
    dst[2]=pack2(f1.x,f1.y); dst[3]=pack2(f1.z,f1.w);
    dst[4]=pack2(f2.x,f2.y); dst[5]=pack2(f2.z,f2.w);
    dst[6]=pack2(f3.x,f3.y); dst[7]=pack2(f3.z,f3.w);
    __syncthreads();
    int n_ = t >> 2, k0 = (t & 3) << 4;
    unsigned obuf[8];
#pragma unroll
    for (int i = 0; i < 8; i++)
        obuf[i] = (unsigned)lt[k0 + 2*i][n_] | ((unsigned)lt[k0 + 2*i + 1][n_] << 16);
    unsigned short* out = O + (size_t)(nb*64 + n_) * K + kb*64 + k0;
    ((uint4*)out)[0] = *(uint4*)&obuf[0];
    ((uint4*)out)[1] = *(uint4*)&obuf[4];
}

// ---------------- row LayerNorm (LN1): x[SEQ][1024] f32 -> bf16 ----------------
__global__ __launch_bounds__(256) void ln_kernel(const float* __restrict__ x,
                                                 const float* __restrict__ g,
                                                 const float* __restrict__ b,
                                                 unsigned short* __restrict__ out) {
    int row = blockIdx.x, t = threadIdx.x;
    float4 v = ((const float4*)(x + (size_t)row * D_MODEL))[t];
    float s  = v.x + v.y + v.z + v.w;
    float sq = v.x*v.x + v.y*v.y + v.z*v.z + v.w*v.w;
#pragma unroll
    for (int m = 1; m < 64; m <<= 1) { s += __shfl_xor(s, m, 64); sq += __shfl_xor(sq, m, 64); }
    __shared__ float ls[4], lq[4];
    int wave = t >> 6, lane = t & 63;
    if (lane == 0) { ls[wave] = s; lq[wave] = sq; }
    __syncthreads();
    s  = ls[0]+ls[1]+ls[2]+ls[3];
    sq = lq[0]+lq[1]+lq[2]+lq[3];
    float mu  = s * (1.0f / D_MODEL);
    float var = sq * (1.0f / D_MODEL) - mu * mu;
    float rs  = rsqrtf(var + 1e-5f);
    int c = t * 4;
    float y0 = (v.x - mu) * rs * g[c+0] + b[c+0];
    float y1 = (v.y - mu) * rs * g[c+1] + b[c+1];
    float y2 = (v.z - mu) * rs * g[c+2] + b[c+2];
    float y3 = (v.w - mu) * rs * g[c+3] + b[c+3];
    unsigned* o = (unsigned*)(out + (size_t)row * D_MODEL + c);
    o[0] = pack2(y0, y1); o[1] = pack2(y2, y3);
}

// ---------------- fused residual-reduce + LN2: x1 = x + b_out + sum(4 parts); x2n = LN(x1) ----------------
__global__ __launch_bounds__(256) void reduce_ln(const float* __restrict__ x,
                                                 const float* __restrict__ bout,
                                                 const unsigned short* __restrict__ parts,
                                                 const float* __restrict__ g,
                                                 const float* __restrict__ b,
                                                 float* __restrict__ x1,
                                                 unsigned short* __restrict__ x2n) {
    int row = blockIdx.x, t = threadIdx.x;
    int i = row * 256 + t;
    float4 v = ((const float4*)x)[i];
    float4 bb = ((const float4*)bout)[t];
    v.x += bb.x; v.y += bb.y; v.z += bb.z; v.w += bb.w;
#pragma unroll
    for (int p = 0; p < 4; p++) {
        ushort4 u = ((const ushort4*)(parts + (size_t)p * SEQ * D_MODEL))[i];
        v.x += bf2f(u.x); v.y += bf2f(u.y); v.z += bf2f(u.z); v.w += bf2f(u.w);
    }
    ((float4*)x1)[i] = v;
    float s  = v.x + v.y + v.z + v.w;
    float sq = v.x*v.x + v.y*v.y + v.z*v.z + v.w*v.w;
#pragma unroll
    for (int m = 1; m < 64; m <<= 1) { s += __shfl_xor(s, m, 64); sq += __shfl_xor(sq, m, 64); }
    __shared__ float ls[4], lq[4];
    int wave = t >> 6, lane = t & 63;
    if (lane == 0) { ls[wave] = s; lq[wave] = sq; }
    __syncthreads();
    s  = ls[0]+ls[1]+ls[2]+ls[3];
    sq = lq[0]+lq[1]+lq[2]+lq[3];
    float mu  = s * (1.0f / D_MODEL);
    float var = sq * (1.0f / D_MODEL) - mu * mu;
    float rs  = rsqrtf(var + 1e-5f);
    int c = t * 4;
    float y0 = (v.x - mu) * rs * g[c+0] + b[c+0];
    float y1 = (v.y - mu) * rs * g[c+1] + b[c+1];
    float y2 = (v.z - mu) * rs * g[c+2] + b[c+2];
    float y3 = (v.w - mu) * rs * g[c+3] + b[c+3];
    unsigned* o = (unsigned*)(x2n + (size_t)row * D_MODEL + c);
    o[0] = pack2(y0, y1); o[1] = pack2(y2, y3);
}

// ---------------- final reduce: out = x1 + b_ff2 + sum(4 partials) ----------------
__global__ __launch_bounds__(256) void reduce_ff2(const float* __restrict__ res,
                                                  const float* __restrict__ bias,
                                                  const unsigned short* __restrict__ parts,
                                                  float* __restrict__ out) {
    int i = blockIdx.x * 256 + threadIdx.x;
    float4 r = ((const float4*)res)[i];
    float4 b = ((const float4*)bias)[i & (D_MODEL/4 - 1)];
    r.x += b.x; r.y += b.y; r.z += b.z; r.w += b.w;
#pragma unroll
    for (int p = 0; p < 4; p++) {
        ushort4 u = ((const ushort4*)(parts + (size_t)p * SEQ * D_MODEL))[i];
        r.x += bf2f(u.x); r.y += bf2f(u.y); r.z += bf2f(u.z); r.w += bf2f(u.w);
    }
    ((float4*)out)[i] = r;
}

// ============ FF GEMM core: BM=128 BN=256 BK=64, 512 thr / 8 waves, counted vmcnt ============
// Full-chip grids (256 blocks). Proven zero-conflict LDS layout: [row][64 u16] rows (128B
// stride) with 8-chunk XOR pos = c ^ (row&7); DMA linear dest + pre-swizzled source.
// Pipeline: stage tiles 0,1 (12 loads/thread); per tile: vmcnt(6) [next tile's 6 stay in
// flight across the barrier] -> s_barrier -> 2x16 MFMA (k-halves) -> s_barrier -> stage(t+2).
#define BMf 128
#define BNf 256
#define FBUF_U16 ((BMf + BNf) * 64)     // 24576 u16 = 48 KB per buffer
#define FSMEM_U16 (2 * FBUF_U16)        // 98304 B total -> 1 block/CU, 8 waves
__device__ __forceinline__ void gemm_core_ff(const unsigned short* __restrict__ A,
                                             const unsigned short* __restrict__ Bt,
                                             int K, int K0, int KS, int bm, int bn,
                                             unsigned short* smem, f32x4 acc[4][4],
                                             int w, int lane) {
    int quad = lane >> 4, lr = lane & 15;
    int wm = w >> 2, wn = w & 3;
    // staging: per tile per thread 2 A + 4 B gl_lds16 (A 16KB + B 32KB = 48 wave-KB / 8 waves)
    const unsigned short* pa[2]; int da[2];
#pragma unroll
    for (int i = 0; i < 2; i++) {
        int rl = w*16 + i*8 + (lane >> 3);
        int sc = (lane & 7) ^ (rl & 7);
        pa[i] = A + (size_t)(bm*BMf + rl) * K + K0 + sc*8;
        da[i] = (w*16 + i*8) * 64;
    }
    const unsigned short* pb[4]; int db[4];
#pragma unroll
    for (int i = 0; i < 4; i++) {
        int rl = w*32 + i*8 + (lane >> 3);
        int sc = (lane & 7) ^ (rl & 7);
        pb[i] = Bt + (size_t)(bn*BNf + rl) * K + K0 + sc*8;
        db[i] = BMf*64 + (w*32 + i*8) * 64;
    }
    // fragment offsets: k-half h -> chunk (quad + 4h) ^ (row&7)
    int foA[2][4], foB[2][4];
#pragma unroll
    for (int i = 0; i < 4; i++) {
        int ra = wm*64 + i*16 + lr;
        foA[0][i] = ra*64 + ((quad     ^ (ra & 7)))*8;
        foA[1][i] = ra*64 + (((quad+4) ^ (ra & 7)))*8;
        int rb = wn*64 + i*16 + lr;
        foB[0][i] = BMf*64 + rb*64 + ((quad     ^ (rb & 7)))*8;
        foB[1][i] = BMf*64 + rb*64 + (((quad+4) ^ (rb & 7)))*8;
    }
    int T = KS >> 6;
    // prologue: stage tiles 0 and 1 (12 outstanding/thread)
#pragma unroll
    for (int t = 0; t < 2; t++) {
        unsigned short* s = smem + t * FBUF_U16;
#pragma unroll
        for (int i = 0; i < 2; i++) gl_lds16(pa[i] + t*64, s + da[i]);
#pragma unroll
        for (int i = 0; i < 4; i++) gl_lds16(pb[i] + t*64, s + db[i]);
    }
    for (int t = 0; t < T; t++) {
        if (t + 1 < T) asm volatile("s_waitcnt vmcnt(6)" ::: "memory");
        else           asm volatile("s_waitcnt vmcnt(0)" ::: "memory");
        __builtin_amdgcn_s_barrier();
        const unsigned short* s = smem + (t & 1) * FBUF_U16;
#pragma unroll
        for (int h = 0; h < 2; h++) {
            bf16x8 af[4], bfr[4];
#pragma unroll
            for (int i = 0; i < 4; i++) af[i]  = ld_frag(s + foA[h][i]);
#pragma unroll
            for (int j = 0; j < 4; j++) bfr[j] = ld_frag(s + foB[h][j]);
            __builtin_amdgcn_s_setprio(1);
#pragma unroll
            for (int i = 0; i < 4; i++)
#pragma unroll
                for (int j = 0; j < 4; j++)
                    acc[i][j] = MFMA16(af[i], bfr[j], acc[i][j]);
            __builtin_amdgcn_s_setprio(0);
        }
        __builtin_amdgcn_s_barrier();    // all waves done reading buf (t&1)
        if (t + 2 < T) {
            unsigned short* sn = smem + (t & 1) * FBUF_U16;
#pragma unroll
            for (int i = 0; i < 2; i++) gl_lds16(pa[i] + (t+2)*64, sn + da[i]);
#pragma unroll
            for (int i = 0; i < 4; i++) gl_lds16(pb[i] + (t+2)*64, sn + db[i]);
        }
    }
}

__device__ __forceinline__ void acc_init(f32x4 acc[4][4]) {
    f32x4 z = {0.f, 0.f, 0.f, 0.f};
#pragma unroll
    for (int i = 0; i < 4; i++)
#pragma unroll
        for (int j = 0; j < 4; j++) acc[i][j] = z;
}

// ---------------- FF1: BM128xBN256 + bias + GELU -> bf16 (grid 16x16 = 256 blocks) ----------------
__global__ __launch_bounds__(512, 2) void k_gemm_ff1(const unsigned short* __restrict__ A,
                                                     const unsigned short* __restrict__ Bt,
                                                     const float* __restrict__ bias,
                                                     unsigned short* __restrict__ C,
                                                     int M, int N, int K) {
    __shared__ unsigned short smem[FSMEM_U16];
    int t = threadIdx.x, w = t >> 6, lane = t & 63;
    int bn = blockIdx.x, bm = blockIdx.y;
    int quad = lane >> 4, lr = lane & 15;
    f32x4 acc[4][4];
    acc_init(acc);
    gemm_core_ff(A, Bt, K, 0, K, bm, bn, smem, acc, w, lane);
    int wm = w >> 2, wn = w & 3;
#pragma unroll
    for (int j = 0; j < 4; j++) {
        int col = bn*BNf + wn*64 + j*16 + lr;
        float bvv = bias[col];
#pragma unroll
        for (int i = 0; i < 4; i++) {
            int row0 = bm*BMf + wm*64 + i*16 + quad*4;
#pragma unroll
            for (int r = 0; r < 4; r++) {
                float v = acc[i][j][r] + bvv;
                v = 0.5f * v * (1.0f + erff(v * 0.70710678118654752f));
                C[(size_t)(row0 + r) * N + col] = f2bf(v);
            }
        }
    }
}

// ---------------- FF2: BM128xBN256, split-K=4 bf16 partials (grid 4x16x4 = 256 blocks) ----------------
__global__ __launch_bounds__(512, 2) void k_gemm_ff2(const unsigned short* __restrict__ A,
                                                     const unsigned short* __restrict__ Bt,
                                                     unsigned short* __restrict__ C,
                                                     int M, int N, int K) {
    __shared__ unsigned short smem[FSMEM_U16];
    int t = threadIdx.x, w = t >> 6, lane = t & 63;
    int bn = blockIdx.x, bm = blockIdx.y, kz = blockIdx.z;
    int quad = lane >> 4, lr = lane & 15;
    int KS = K >> 2;
    f32x4 acc[4][4];
    acc_init(acc);
    gemm_core_ff(A, Bt, K, kz*KS, KS, bm, bn, smem, acc, w, lane);
    int wm = w >> 2, wn = w & 3;
    unsigned short* P = C + (size_t)kz * M * N;
#pragma unroll
    for (int j = 0; j < 4; j++) {
        int col = bn*BNf + wn*64 + j*16 + lr;
#pragma unroll
        for (int i = 0; i < 4; i++) {
            int row0 = bm*BMf + wm*64 + i*16 + quad*4;
#pragma unroll
            for (int r = 0; r < 4; r++)
                P[(size_t)(row0 + r) * N + col] = f2bf(acc[i][j][r]);
        }
    }
}

// ---------------- GEMM core v4b: TM=128 TN=128 BK=64, 512 threads, 8 waves (QKV/OP) ----------------
#define TMg 128
#define TNg 128
#define HALFg ((TMg + TNg) * 64)        // 16384 u16 = 32 KB per buffer
#define SMEM_U16 (2 * HALFg)            // 65536 B total
__device__ __forceinline__ void gemm_core512(const unsigned short* __restrict__ A,
                                             const unsigned short* __restrict__ Bt,
                                             int K, int K0, int KS, int bm, int bn,
                                             unsigned short* smem, f32x4 acc[4][4],
                                             int w, int lane) {
    int quad = lane >> 4, lr = lane & 15;
    int kg = w >> 2;
    const unsigned short* pa[2]; const unsigned short* pb[2];
    int aoff[2], boff[2];
#pragma unroll
    for (int i = 0; i < 2; i++) {
        int rl = i*64 + w*8 + (lane >> 3);
        int sc = (lane & 7) ^ (rl & 7);
        pa[i] = A  + (size_t)(bm*TMg + rl) * K + K0 + sc*8;
        pb[i] = Bt + (size_t)(bn*TNg + rl) * K + K0 + sc*8;
        aoff[i] = (i*64 + w*8) * 64;
        boff[i] = TMg*64 + (i*64 + w*8) * 64;
    }
    int wr = ((w >> 1) & 1) * 64, wc = (w & 1) * 64;
    int foA[4], foB[4];
#pragma unroll
    for (int i = 0; i < 4; i++) {
        int ra = wr + i*16 + lr;
        foA[i] = ra*64 + (((quad + 4*kg) ^ (ra & 7)))*8;
        int rb = wc + i*16 + lr;
        foB[i] = TMg*64 + rb*64 + (((quad + 4*kg) ^ (rb & 7)))*8;
    }
#pragma unroll
    for (int i = 0; i < 2; i++) { gl_lds16(pa[i], smem + aoff[i]); gl_lds16(pb[i], smem + boff[i]); }
    int bo = 0;
    int T = KS >> 6;
    for (int t = 0; t < T; t++) {
        __syncthreads();
        if (t + 1 < T) {
            int nb = bo ^ HALFg;
#pragma unroll
            for (int i = 0; i < 2; i++) {
                gl_lds16(pa[i] + (t+1)*64, smem + nb + aoff[i]);
                gl_lds16(pb[i] + (t+1)*64, smem + nb + boff[i]);
            }
        }
        const unsigned short* s = smem + bo;
        bf16x8 af[4], bfr[4];
#pragma unroll
        for (int i = 0; i < 4; i++) af[i] = ld_frag(s + foA[i]);
#pragma unroll
        for (int j = 0; j < 4; j++) bfr[j] = ld_frag(s + foB[j]);
        __builtin_amdgcn_s_setprio(1);
#pragma unroll
        for (int i = 0; i < 4; i++)
#pragma unroll
            for (int j = 0; j < 4; j++)
                acc[i][j] = MFMA16(af[i], bfr[j], acc[i][j]);
        __builtin_amdgcn_s_setprio(0);
        bo ^= HALFg;
    }
}

// split-merge, literal-index version (rule #20 safe).
__device__ __forceinline__ void acc_merge_split(unsigned short* smem, f32x4 acc[4][4],
                                                int w, int lane) {
    float* X = (float*)smem;
    int kg = w >> 2, p = w & 3, quad = lane >> 4, lr = lane & 15;
    if (kg) {
#pragma unroll
        for (int i = 0; i < 4; i++) {
            f32x4 t0 = acc[i][0]; acc[i][0] = acc[i][2]; acc[i][2] = t0;
            f32x4 t1 = acc[i][1]; acc[i][1] = acc[i][3]; acc[i][3] = t1;
        }
    }
    __syncthreads();
    int g = (kg ^ 1) * 2;
#pragma unroll
    for (int i = 0; i < 4; i++)
#pragma unroll
        for (int r = 0; r < 4; r++) {
            int ro = (i*16 + r*4 + quad)*16 + lr;
            X[(p*4 + g    )*1024 + ro] = acc[i][2][r];
            X[(p*4 + g + 1)*1024 + ro] = acc[i][3][r];
        }
    __syncthreads();
    int k = kg * 2;
#pragma unroll
    for (int i = 0; i < 4; i++)
#pragma unroll
        for (int r = 0; r < 4; r++) {
            int ro = (i*16 + r*4 + quad)*16 + lr;
            acc[i][0][r] += X[(p*4 + k    )*1024 + ro];
            acc[i][1][r] += X[(p*4 + k + 1)*1024 + ro];
        }
}

// ---------------- QKV GEMM + fused q/k-normalize + v-transpose epilogue ----------------
__global__ __launch_bounds__(512, 4) void k_gemm_qkv(const unsigned short* __restrict__ A,
                                                     const unsigned short* __restrict__ Bt,
                                                     const float* __restrict__ bias,
                                                     unsigned short* __restrict__ qn,
                                                     unsigned short* __restrict__ kn,
                                                     unsigned short* __restrict__ vt) {
    __shared__ unsigned short smem[SMEM_U16];
    int t = threadIdx.x;
    int bn = blockIdx.x, bm = blockIdx.y;
    int w = t >> 6, lane = t & 63;
    int quad = lane >> 4, lr = lane & 15;
    f32x4 acc[4][4];
    acc_init(acc);
    gemm_core512(A, Bt, 1024, 0, 1024, bm, bn, smem, acc, w, lane);

    float* X = (float*)smem;
    int kg = w >> 2, p = w & 3;
    __syncthreads();
    if (kg == 1) {
#pragma unroll
        for (int j = 0; j < 4; j++) {
            float* slot = X + (p*4 + j)*1024;
#pragma unroll
            for (int i = 0; i < 4; i++)
#pragma unroll
                for (int r = 0; r < 4; r++)
                    slot[(i*16 + r*4 + quad)*16 + lr] = acc[i][j][r];
        }
    }
    __syncthreads();
    int wr = ((w >> 1) & 1) * 64, wc = (w & 1) * 64;
    int sec = bn >> 3, hp = bn & 7;
    if (kg == 0) {
#pragma unroll
        for (int j = 0; j < 4; j++) {
            const float* slot = X + (p*4 + j)*1024;
            float bv = bias[bn*TNg + wc + j*16 + lr];
#pragma unroll
            for (int i = 0; i < 4; i++)
#pragma unroll
                for (int r = 0; r < 4; r++)
                    acc[i][j][r] += slot[(i*16 + r*4 + quad)*16 + lr] + bv;
        }
    }

    if (sec < 2) {
        if (kg == 0) {
            int h = hp*2 + (w & 1);
            unsigned short* dst = (sec == 0) ? qn : kn;
            float mul = (sec == 0) ? 0.125f : 1.0f;   // fold 1/sqrt(HD) into q
#pragma unroll
            for (int i = 0; i < 4; i++)
#pragma unroll
                for (int r = 0; r < 4; r++) {
                    float ss = 0.f;
#pragma unroll
                    for (int j = 0; j < 4; j++) ss += acc[i][j][r]*acc[i][j][r];
                    ss += __shfl_xor(ss, 1, 64); ss += __shfl_xor(ss, 2, 64);
                    ss += __shfl_xor(ss, 4, 64); ss += __shfl_xor(ss, 8, 64);
                    float scale = mul / fmaxf(sqrtf(ss), 1e-12f);
                    int row = bm*TMg + wr + i*16 + quad*4 + r;
                    size_t base = ((size_t)h*SEQ + row) * HD;
#pragma unroll
                    for (int j = 0; j < 4; j++)
                        dst[base + j*16 + lr] = f2bf(acc[i][j][r] * scale);
                }
        }
    } else {
        __syncthreads();
        unsigned short (*lv)[136] = (unsigned short (*)[136])smem;
        if (kg == 0) {
#pragma unroll
            for (int i = 0; i < 4; i++)
#pragma unroll
                for (int j = 0; j < 4; j++)
#pragma unroll
                    for (int r = 0; r < 4; r++)
                        lv[wc + j*16 + lr][wr + i*16 + quad*4 + r] = f2bf(acc[i][j][r]);
        }
        __syncthreads();
        int d = t >> 2, l0 = (t & 3) * 32;
        unsigned short* ov = vt + ((size_t)(hp*128 + d)) * SEQ + bm*TMg + l0;
#pragma unroll
        for (int c = 0; c < 4; c++)
            ((uint4*)ov)[c] = *(uint4*)&lv[d][l0 + c*8];
    }
}

// ---------------- OP split-K partial-output GEMM (bf16 partial slices) ----------------
template<int SPLITK>
__device__ __forceinline__ void gemm_part512(const unsigned short* A, const unsigned short* Bt,
                                             unsigned short* C, int M, int N, int K) {
    __shared__ unsigned short smem[SMEM_U16];
    int t = threadIdx.x;
    int bn = blockIdx.x, bm = blockIdx.y, kz = blockIdx.z;
    int w = t >> 6, lane = t & 63;
    int quad = lane >> 4, lr = lane & 15;
    int KS = K / SPLITK;
    f32x4 acc[4][4];
    acc_init(acc);
    gemm_core512(A, Bt, K, kz*KS, KS, bm, bn, smem, acc, w, lane);
    acc_merge_split(smem, acc, w, lane);
    int kg = w >> 2, wr = ((w >> 1) & 1) * 64, wc = (w & 1) * 64;
    unsigned short* P = C + (size_t)kz * M * N;
    int col0 = bn*TNg + wc + (kg*2)*16 + lr;
    int col1 = col0 + 16;
#pragma unroll
    for (int i = 0; i < 4; i++) {
        int row0 = bm*TMg + wr + i*16 + quad*4;
#pragma unroll
        for (int r = 0; r < 4; r++) {
            P[(size_t)(row0 + r) * N + col0] = f2bf(acc[i][0][r]);
            P[(size_t)(row0 + r) * N + col1] = f2bf(acc[i][1][r]);
        }
    }
}
__global__ __launch_bounds__(512, 4) void k_gemm_op(const unsigned short* A, const unsigned short* Bt,
                                                    unsigned short* C, int M, int N, int K) {
    gemm_part512<4>(A, Bt, C, M, N, K);
}

// ---------------- attention: key-split KSPLIT=2, single-pass softmax ----------------
#define KSPLIT 2
#define KTILES (SEQ / 64 / KSPLIT)   // 16
__global__ __launch_bounds__(256) void attn_kernel(const unsigned short* __restrict__ qn,
                                                   const unsigned short* __restrict__ kn,
                                                   const unsigned short* __restrict__ vt,
                                                   const float* __restrict__ lcc,
                                                   float* __restrict__ num_ws,
                                                   float* __restrict__ den_ws) {
    __shared__ unsigned short lQP[64*64];      // Q then P (per-wave own stripe)
    __shared__ unsigned short lK[2][64*64];    // [key][d], swizzled chunks
    __shared__ unsigned short lV[2][64*64];    // [d][key], swizzled chunks
    int h = blockIdx.x, qb = blockIdx.y, kz = blockIdx.z;
    int t = threadIdx.x;
    int wave = t >> 6, lane = t & 63, quad = lane >> 4, lr = lane & 15;
    int r0 = lane >> 3;            // row within 8-row DMA group
    int ch = lane & 7;             // linear dest chunk

    const unsigned short* kn0 = kn + (size_t)h*SEQ*HD + (size_t)kz*(SEQ/KSPLIT)*HD;
    const unsigned short* vt0 = vt + (size_t)h*HD*SEQ + kz*(SEQ/KSPLIT);
    const float* lcc0 = lcc + kz*(SEQ/KSPLIT);

#pragma unroll
    for (int i = 0; i < 2; i++) {
        int rl = wave*16 + i*8 + r0;
        int ss = ch ^ (rl & 7);
        gl_lds16(qn + ((size_t)h*SEQ + qb*64 + rl)*HD + ss*8, lQP + (wave*16 + i*8)*64);
        gl_lds16(kn0 + (size_t)rl*HD + ss*8,                  lK[0] + (wave*16 + i*8)*64);
        gl_lds16(vt0 + (size_t)rl*SEQ + ss*8,                 lV[0] + (wave*16 + i*8)*64);
    }
    __syncthreads();

    bf16x8 aq0 = ld_frag(lQP + (wave*16 + lr)*64 + ((quad     ^ (lr & 7)))*8);
    bf16x8 aq1 = ld_frag(lQP + (wave*16 + lr)*64 + (((quad+4) ^ (lr & 7)))*8);

    f32x4 z = {0.f, 0.f, 0.f, 0.f};
    f32x4 oacc[4]; oacc[0]=z; oacc[1]=z; oacc[2]=z; oacc[3]=z;
    float den[4] = {0.f, 0.f, 0.f, 0.f};

    int cur = 0;
    for (int kb = 0; kb < KTILES; kb++) {
        if (kb + 1 < KTILES) {
            int nxt = cur ^ 1;
#pragma unroll
            for (int i = 0; i < 2; i++) {
                int rl = wave*16 + i*8 + r0;
                int ss = ch ^ (rl & 7);
                gl_lds16(kn0 + (size_t)(kb+1)*64*HD + (size_t)rl*HD + ss*8,
                         lK[nxt] + (wave*16 + i*8)*64);
                gl_lds16(vt0 + (size_t)rl*SEQ + (kb+1)*64 + ss*8,
                         lV[nxt] + (wave*16 + i*8)*64);
            }
        }
        float lmv[4];
#pragma unroll
        for (int j = 0; j < 4; j++) lmv[j] = 0.05f * lcc0[kb*64 + j*16 + lr];

        __builtin_amdgcn_s_setprio(1);
        const unsigned short* Kc = lK[cur];
#pragma unroll
        for (int j = 0; j < 4; j++) {
            bf16x8 b0 = ld_frag(Kc + (j*16 + lr)*64 + ((quad     ^ (lr & 7)))*8);
            bf16x8 b1 = ld_frag(Kc + (j*16 + lr)*64 + (((quad+4) ^ (lr & 7)))*8);
            f32x4 s = z;
            s = MFMA16(aq0, b0, s);
            s = MFMA16(aq1, b1, s);
#pragma unroll
            for (int r = 0; r < 4; r++) {
                float p = __expf(s[r] + lmv[j]);
                den[r] += p;
                int prow = wave*16 + quad*4 + r;
                lQP[prow*64 + (((2*j + (lr >> 3)) ^ (prow & 7)))*8 + (lr & 7)] = f2bf(p);
            }
        }
        bf16x8 ap0 = ld_frag(lQP + (wave*16 + lr)*64 + ((quad     ^ (lr & 7)))*8);
        bf16x8 ap1 = ld_frag(lQP + (wave*16 + lr)*64 + (((quad+4) ^ (lr & 7)))*8);
        const unsigned short* Vc = lV[cur];
#pragma unroll
        for (int j2 = 0; j2 < 4; j2++) {
            bf16x8 b0 = ld_frag(Vc + (j2*16 + lr)*64 + ((quad     ^ (lr & 7)))*8);
            bf16x8 b1 = ld_frag(Vc + (j2*16 + lr)*64 + (((quad+4) ^ (lr & 7)))*8);
            oacc[j2] = MFMA16(ap0, b0, oacc[j2]);
            oacc[j2] = MFMA16(ap1, b1, oacc[j2]);
        }
        __builtin_amdgcn_s_setprio(0);
        __syncthreads();
        cur ^= 1;
    }
#pragma unroll
    for (int r = 0; r < 4; r++)
#pragma unroll
        for (int m = 1; m < 16; m <<= 1) den[r] += __shfl_xor(den[r], m, 64);

    float* nump = num_ws + (((size_t)(h*32 + qb)) * KSPLIT + kz) * 4096;
#pragma unroll
    for (int j2 = 0; j2 < 4; j2++)
#pragma unroll
        for (int r = 0; r < 4; r++)
            nump[(wave*16 + quad*4 + r) * 64 + j2*16 + lr] = oacc[j2][r];
    if (lr == 0) {
        float* denp = den_ws + (((size_t)(h*32 + qb)) * KSPLIT + kz) * 64;
#pragma unroll
        for (int r = 0; r < 4; r++) denp[wave*16 + quad*4 + r] = den[r];
    }
}

// combine: out[qb*64+row][h*64+col] = sum_kz num / sum_kz den
__global__ __launch_bounds__(256) void attn_comb(const float* __restrict__ num_ws,
                                                 const float* __restrict__ den_ws,
                                                 unsigned short* __restrict__ attn) {
    int hq = blockIdx.x;          // h*32+qb
    int h = hq >> 5, qb = hq & 31;
    int t = threadIdx.x;
    int row = t >> 2, col0 = (t & 3) << 4;
    const float* n0 = num_ws + ((size_t)hq * KSPLIT) * 4096 + row*64 + col0;
    const float* n1 = n0 + 4096;
    float d = den_ws[(size_t)hq * KSPLIT * 64 + row] + den_ws[((size_t)hq * KSPLIT + 1) * 64 + row];
    float inv = 1.0f / d;
    unsigned ob[8];
#pragma unroll
    for (int i = 0; i < 4; i++) {
        float4 a = ((const float4*)n0)[i];
        float4 b = ((const float4*)n1)[i];
        ob[2*i]   = pack2((a.x + b.x) * inv, (a.y + b.y) * inv);
        ob[2*i+1] = pack2((a.z + b.z) * inv, (a.w + b.w) * inv);
    }
    unsigned short* op = attn + (size_t)(qb*64 + row) * D_MODEL + h*64 + col0;
    ((uint4*)op)[0] = *(uint4*)&ob[0];
    ((uint4*)op)[1] = *(uint4*)&ob[4];
}

// ---------------- host orchestration ----------------
extern "C" void kernel_launch(void* const* d_in, const int* in_sizes, int n_in,
                              void* d_out, int out_size, void* d_ws, size_t ws_size,
                              hipStream_t stream) {
    const float* x      = (const float*)d_in[0];
    const float* lcc    = (const float*)d_in[1];
    const float* w_qkv  = (const float*)d_in[2];
    const float* b_qkv  = (const float*)d_in[3];
    const float* w_out  = (const float*)d_in[4];
    const float* b_out  = (const float*)d_in[5];
    const float* ln1_g  = (const float*)d_in[6];
    const float* ln1_b  = (const float*)d_in[7];
    const float* ln2_g  = (const float*)d_in[8];
    const float* ln2_b  = (const float*)d_in[9];
    const float* w_ff1  = (const float*)d_in[10];
    const float* b_ff1  = (const float*)d_in[11];
    const float* w_ff2  = (const float*)d_in[12];
    const float* b_ff2  = (const float*)d_in[13];

    char* ws = (char*)d_ws;
    unsigned short* wtq  = (unsigned short*)(ws);                    // -> 6291456
    unsigned short* wto  = (unsigned short*)(ws + 6291456);          // -> 8388608
    unsigned short* wtf1 = (unsigned short*)(ws + 8388608);          // -> 16777216
    unsigned short* wtf2 = (unsigned short*)(ws + 16777216);         // -> 25165824
    unsigned short* xn   = (unsigned short*)(ws + 25165824);         // -> 29360128
    float*          x1   = (float*)(ws + 29360128);                  // 2048x1024 f32 -> 37748736
    float*          numw = (float*)(ws + 29360128);                  // alias: attn num partials (16.8MB)
    float*          denw = (float*)(ws + 46137344);                  // 256KB attn den partials
    unsigned short* hbuf = (unsigned short*)(ws + 37748736);         // 2048x4096 bf16 -> 54525952
    unsigned short* pOP  = (unsigned short*)(ws + 37748736);         // alias: 4 bf16 slices = 16MB
    unsigned short* qnb  = (unsigned short*)(ws + 54525952);         // -> 58720256
    unsigned short* knb  = (unsigned short*)(ws + 58720256);         // -> 62914560
    unsigned short* vtb  = (unsigned short*)(ws + 62914560);         // -> 67108864
    unsigned short* pFF2 = (unsigned short*)(ws);                    // alias (weights dead): exactly 16777216B
    unsigned short* attnb = xn;                                      // alias (xn dead after QKV gemm)
    unsigned short* x2n  = qnb;                                      // alias (qn dead after attention)
    float* outp = (float*)d_out;

    // Ordering (sequential stream): numw aliases x1 region — attn partials consumed by
    // attn_comb before reduce_ln writes x1. pOP (16MB, ends at qnb) overlaps numw tail and
    // denw — both dead once attn_comb ran; OP gemm runs after attn_comb. pFF2 overwrites
    // wtq/wto/wtf1 (dead), ends exactly at wtf2 (still live for FF2 reads).

    wcast_all<<<3072, 256, 0, stream>>>(w_qkv, w_out, w_ff1, w_ff2, wtq, wto, wtf1, wtf2);
    ln_kernel<<<SEQ, 256, 0, stream>>>(x, ln1_g, ln1_b, xn);
    k_gemm_qkv<<<dim3(24, 16), 512, 0, stream>>>(xn, wtq, b_qkv, qnb, knb, vtb);
    attn_kernel<<<dim3(16, 32, KSPLIT), 256, 0, stream>>>(qnb, knb, vtb, lcc, numw, denw);
    attn_comb<<<512, 256, 0, stream>>>(numw, denw, attnb);
    k_gemm_op<<<dim3(8, 16, 4), 512, 0, stream>>>(attnb, wto, pOP, SEQ, 1024, 1024);
    reduce_ln<<<SEQ, 256, 0, stream>>>(x, b_out, pOP, ln2_g, ln2_b, x1, x2n);
    k_gemm_ff1<<<dim3(16, 16), 512, 0, stream>>>(x2n, wtf1, b_ff1, hbuf, SEQ, 4096, 1024);
    k_gemm_ff2<<<dim3(4, 16, 4), 512, 0, stream>>>(hbuf, wtf2, pFF2, SEQ, 1024, 4096);
    reduce_ff2<<<SEQ*D_MODEL/1024, 256, 0, stream>>>(x1, b_ff2, pFF2, outp);
}